// Round 1
// baseline (294.757 us; speedup 1.0000x reference)
//
#include <hip/hip_runtime.h>

// out[b,o] = x[b,:] @ W_lin[:,o] + x[b] @ W_nl[o] @ x[b]
// GEMM out = z @ Wz, z[b, 32i+j] = x[b,i]*x[b,j] (K=1024) + linear tail,
// via v_mfma_f32_16x16x32_bf16. K is split EIGHT ways across the block's
// waves: wave w owns ks in [4w, 4w+4) and keeps its B-fragments in registers
// (8 x bf16x8 = 32 VGPRs -> ~75 total regs -> 6 waves/SIMD, vs 3 for the
// old 4-way split). Linear part uses bf16(W_lin/8) in every wave (exact
// pow2 scale). The 8 partials are reduced via LDS with WIDE ops both ways:
// layout [col32][granule-swizzled (4w+q)][row4] so writes are 2x b128/lane
// and 128 reducer threads gather 8x b128 each, both conflict-free.

typedef __attribute__((ext_vector_type(8))) __bf16 bf16x8;
typedef __attribute__((ext_vector_type(4))) float floatx4;

#define NB     524288
#define NTILES (NB / 16)   // 32768
#define GRID   2048        // 16 tiles per block, exact
#define RBUF   4096        // floats per reduce buffer: 32 cols * 32 granules * 4

__global__ __launch_bounds__(512, 6)
void nnode_kernel(const float* __restrict__ x, const float* __restrict__ Wlin,
                  const float* __restrict__ Wnl, float* __restrict__ out) {
    __shared__ float red[2][RBUF];   // 2 * 16 KiB = 32 KiB

    const int tid  = threadIdx.x;
    const int wave = tid >> 6;   // 0..7
    const int lane = tid & 63;
    const int q    = lane >> 4;  // 0..3: A k-window / C row group
    const int col  = lane & 15;  // output column / A row

    // ---- B fragments for this wave's 4 ks values, kept in registers ----
    // B[k = q*8+j][n = col+16t] = W_nl[o = col+16t][i = ks][j' = q*8+j]
    bf16x8 bW[4][2];
    #pragma unroll
    for (int kl = 0; kl < 4; ++kl) {
        const int ks = wave * 4 + kl;
        #pragma unroll
        for (int t = 0; t < 2; ++t) {
            const float* src = Wnl + (size_t)(col + 16 * t) * 1024 + ks * 32 + q * 8;
            floatx4 a = *(const floatx4*)(src);
            floatx4 b = *(const floatx4*)(src + 4);
            bf16x8 v;
            #pragma unroll
            for (int j = 0; j < 4; ++j) { v[j] = (__bf16)a[j]; v[j + 4] = (__bf16)b[j]; }
            bW[kl][t] = v;
        }
    }
    // ---- linear-part B fragments, 1/8-scaled (all 8 waves add 1/8) ----
    bf16x8 bl0, bl1;
    #pragma unroll
    for (int j = 0; j < 8; ++j) {
        bl0[j] = (__bf16)(0.125f * Wlin[(q * 8 + j) * 32 + col]);
        bl1[j] = (__bf16)(0.125f * Wlin[(q * 8 + j) * 32 + col + 16]);
    }

    // LDS granule swizzle: within column-block c, partial (w,q) lives at
    // granule (4w + q + R(c)) & 31; R spreads banks across q and col bits.
    const int Rw = ((col & 1) << 2) | (col & 2);
    const int g0 = (4 * wave + q + Rw) & 31;

    // reducer constants (threads 0..127: one (col, row-quad) each)
    const int rcol = tid & 31;
    const int rq   = (tid >> 5) & 3;
    const int Rr   = ((rcol & 1) << 2) | (rcol & 2);

    int it = 0;
    for (int tile = blockIdx.x; tile < NTILES; tile += GRID, ++it) {
        const int b0 = tile << 4;
        const float* xr = x + (size_t)(b0 + col) * 32;

        // this wave's scalars x[m, 4w..4w+4) and the A window x[m, q*8..q*8+8)
        floatx4 s  = *(const floatx4*)(xr + wave * 4);
        floatx4 w0 = *(const floatx4*)(xr + q * 8);
        floatx4 w1 = *(const floatx4*)(xr + q * 8 + 4);

        floatx4 acc0 = {0.f, 0.f, 0.f, 0.f};
        floatx4 acc1 = {0.f, 0.f, 0.f, 0.f};

        // linear tail (1/8-scaled, wave-uniform)
        {
            bf16x8 af;
            #pragma unroll
            for (int j = 0; j < 4; ++j) { af[j] = (__bf16)w0[j]; af[j + 4] = (__bf16)w1[j]; }
            acc0 = __builtin_amdgcn_mfma_f32_16x16x32_bf16(af, bl0, acc0, 0, 0, 0);
            acc1 = __builtin_amdgcn_mfma_f32_16x16x32_bf16(af, bl1, acc1, 0, 0, 0);
        }

        #pragma unroll
        for (int kl = 0; kl < 4; ++kl) {
            const float sc = s[kl];
            bf16x8 af;
            #pragma unroll
            for (int j = 0; j < 4; ++j) {
                af[j]     = (__bf16)(sc * w0[j]);
                af[j + 4] = (__bf16)(sc * w1[j]);
            }
            acc0 = __builtin_amdgcn_mfma_f32_16x16x32_bf16(af, bW[kl][0], acc0, 0, 0, 0);
            acc1 = __builtin_amdgcn_mfma_f32_16x16x32_bf16(af, bW[kl][1], acc1, 0, 0, 0);
        }

        // ---- write partials: acc[r] is row q*4+r, so 4 floats are one
        //      contiguous granule -> one b128 store per acc half ----
        float* rb = red[it & 1];
        *(floatx4*)(rb + col * 128 + g0 * 4)          = acc0;
        *(floatx4*)(rb + (col + 16) * 128 + g0 * 4)   = acc1;
        __syncthreads();

        // ---- 128 threads reduce: each sums 8 waves' granules for one
        //      (col, row-quad), 8x ds_read_b128, then 4 coalesced stores ----
        if (tid < 128) {
            floatx4 sum = {0.f, 0.f, 0.f, 0.f};
            #pragma unroll
            for (int w = 0; w < 8; ++w) {
                const int g = (4 * w + rq + Rr) & 31;
                floatx4 p = *(const floatx4*)(rb + rcol * 128 + g * 4);
                sum.x += p.x; sum.y += p.y; sum.z += p.z; sum.w += p.w;
            }
            float* op = out + (size_t)(b0 + rq * 4) * 32 + rcol;
            op[0]  = sum.x;
            op[32] = sum.y;
            op[64] = sum.z;
            op[96] = sum.w;
        }
        // next tile writes the other buffer; the barrier above orders reuse
    }
}

extern "C" void kernel_launch(void* const* d_in, const int* in_sizes, int n_in,
                              void* d_out, int out_size, void* d_ws, size_t ws_size,
                              hipStream_t stream) {
    const float* x    = (const float*)d_in[0];
    const float* Wlin = (const float*)d_in[1];
    const float* Wnl  = (const float*)d_in[2];
    float* out        = (float*)d_out;
    nnode_kernel<<<dim3(GRID), dim3(512), 0, stream>>>(x, Wlin, Wnl, out);
}

// Round 2
// 171.071 us; speedup vs baseline: 1.7230x; 1.7230x over previous
//
#include <hip/hip_runtime.h>

// out[b,o] = x[b,:] @ W_lin[:,o] + x[b] @ W_nl[o] @ x[b]
// Symmetric GEMM form: fold W' (a,b)-block-pairs of W_nl + W_nl^T so the
// quadratic form needs only 10 8x8 block-pairs (K=640) instead of K=1024:
//   out_nl[b,o] = sum_{pairs (a<=b)} sum_{u,v} x[8a+u] x[8b+v] W'[a,b,u,v,o]
// 20 k-steps of 32 are split across 4 waves (5 each); B'-fragments live in
// registers (10 x bf16x8 = 40 VGPRs). x tiles are staged through a padded,
// double-buffered LDS buffer: ONE coalesced floatx2/thread global load per
// tile, issued a full iteration ahead (prefetch across the barrier), so HBM
// latency hides under compute. Linear part: bf16(0.25*W_lin) in all 4 waves
// (exact pow2 -> partial sums reconstruct it). Partial reduce = round-0's
// proven scheme (one barrier/tile, double-buffered).

typedef __attribute__((ext_vector_type(8))) __bf16 bf16x8;
typedef __attribute__((ext_vector_type(4))) float floatx4;
typedef __attribute__((ext_vector_type(2))) float floatx2;

#define NB     524288
#define NTILES (NB / 16)      // 32768
#define GRID   1024           // 4 blocks/CU resident, 32 iters/block, no tail
#define ITERS  (NTILES / GRID)
#define XROW   36             // padded x-row stride (floats): 144B, 16B-aligned
#define XBUF   (16 * XROW)    // 576 floats = 2304B per buffer
#define REDW   544            // 16 rows * 34 floats
#define REDB   (4 * REDW)

__global__ __launch_bounds__(256, 4)
void nnode_kernel(const float* __restrict__ x, const float* __restrict__ Wlin,
                  const float* __restrict__ Wnl, float* __restrict__ out) {
    __shared__ __align__(16) float xs[2][XBUF];   // 4.5 KiB
    __shared__ __align__(16) float red[2][REDB];  // 17 KiB

    const int tid  = threadIdx.x;
    const int wave = tid >> 6;
    const int lane = tid & 63;
    const int q    = lane >> 4;   // quad: A k-window / C row group
    const int col  = lane & 15;   // output column / A row

    // ---- step table + B' fragments (wave w owns global steps 5w..5w+5) ----
    // step t: pair p=t>>1, half h=t&1; pairs: (0,0)(0,1)(0,2)(0,3)(1,1)(1,2)
    // (1,3)(2,2)(2,3)(3,3). A k-slot (q,j) <-> (u=4h+q, v=j).
    int eoffs[5], woffs[5];
    bf16x8 bW[5][2];
    #pragma unroll
    for (int kl = 0; kl < 5; ++kl) {
        const int t  = wave * 5 + kl;
        const int p  = t >> 1, h = t & 1;
        const int pa = (p < 4) ? 0 : ((p < 7) ? 1 : ((p < 9) ? 2 : 3));
        const int pb = p - ((p < 4) ? 0 : ((p < 7) ? 3 : ((p < 9) ? 5 : 6)));
        eoffs[kl] = 8 * pa + 4 * h;   // scalar element offset (add q per lane)
        woffs[kl] = 8 * pb;           // vector window offset
        const bool diag = (pa == pb);
        const int  i1   = eoffs[kl] + q;          // = 8a + u
        #pragma unroll
        for (int tt = 0; tt < 2; ++tt) {
            const float* base = Wnl + (size_t)(col + 16 * tt) * 1024;
            floatx4 v0 = *(const floatx4*)(base + i1 * 32 + woffs[kl]);
            floatx4 v1 = *(const floatx4*)(base + i1 * 32 + woffs[kl] + 4);
            if (!diag) {   // += W_nl[o, 8b+v, 8a+u]
                #pragma unroll
                for (int j = 0; j < 4; ++j) {
                    v0[j] += base[(size_t)(woffs[kl] + j) * 32 + i1];
                    v1[j] += base[(size_t)(woffs[kl] + 4 + j) * 32 + i1];
                }
            }
            bf16x8 f;
            #pragma unroll
            for (int j = 0; j < 4; ++j) { f[j] = (__bf16)v0[j]; f[j + 4] = (__bf16)v1[j]; }
            bW[kl][tt] = f;
        }
    }

    // ---- linear-part B fragments, quarter-scaled (all 4 waves add 1/4) ----
    bf16x8 bl0, bl1;
    #pragma unroll
    for (int j = 0; j < 8; ++j) {
        bl0[j] = (__bf16)(0.25f * Wlin[(q * 8 + j) * 32 + col]);
        bl1[j] = (__bf16)(0.25f * Wlin[(q * 8 + j) * 32 + col + 16]);
    }

    const int srow  = tid >> 4;          // staging/reduce row 0..15
    const int scol2 = (tid & 15) * 2;    // staging/reduce elem pair

    // ---- prologue: stage tile blockIdx.x into xs[0] ----
    {
        floatx2 v = *(const floatx2*)(x + (size_t)blockIdx.x * 512 + tid * 2);
        *(floatx2*)&xs[0][srow * XROW + scol2] = v;
    }
    __syncthreads();

    for (int it = 0; it < ITERS; ++it) {
        const int b0  = (blockIdx.x + it * GRID) << 4;
        const int cur = it & 1;

        // prefetch next tile (coalesced 2KB/block) -> regs; LDS-write after
        // the partial store, consumed after the barrier at it+1.
        floatx2 pre;
        if (it < ITERS - 1)
            pre = *(const floatx2*)(x + ((size_t)b0 + GRID * 16) * 32 + tid * 2);

        const float* xr = &xs[cur][col * XROW];   // this lane's row base
        floatx4 acc0 = {0.f, 0.f, 0.f, 0.f};
        floatx4 acc1 = {0.f, 0.f, 0.f, 0.f};

        // linear tail (quarter-scaled, window at q*8)
        {
            floatx4 a0 = *(const floatx4*)(xr + q * 8);
            floatx4 a1 = *(const floatx4*)(xr + q * 8 + 4);
            bf16x8 af;
            #pragma unroll
            for (int j = 0; j < 4; ++j) { af[j] = (__bf16)a0[j]; af[j + 4] = (__bf16)a1[j]; }
            acc0 = __builtin_amdgcn_mfma_f32_16x16x32_bf16(af, bl0, acc0, 0, 0, 0);
            acc1 = __builtin_amdgcn_mfma_f32_16x16x32_bf16(af, bl1, acc1, 0, 0, 0);
        }

        // 5 symmetric-packed k-steps: af[j] = x[8a+4h+q] * x[8b+j]
        #pragma unroll
        for (int kl = 0; kl < 5; ++kl) {
            const float sc = xr[eoffs[kl] + q];
            floatx4 w0 = *(const floatx4*)(xr + woffs[kl]);
            floatx4 w1 = *(const floatx4*)(xr + woffs[kl] + 4);
            bf16x8 af;
            #pragma unroll
            for (int j = 0; j < 4; ++j) {
                af[j]     = (__bf16)(sc * w0[j]);
                af[j + 4] = (__bf16)(sc * w1[j]);
            }
            acc0 = __builtin_amdgcn_mfma_f32_16x16x32_bf16(af, bW[kl][0], acc0, 0, 0, 0);
            acc1 = __builtin_amdgcn_mfma_f32_16x16x32_bf16(af, bW[kl][1], acc1, 0, 0, 0);
        }

        // ---- partials to LDS (C/D: row = q*4+r, col = col(+16)) ----
        float* rp = red[cur] + wave * REDW;
        #pragma unroll
        for (int r = 0; r < 4; ++r) {
            rp[(q * 4 + r) * 34 + col]      = acc0[r];
            rp[(q * 4 + r) * 34 + col + 16] = acc1[r];
        }
        // land the prefetched x tile into the other x buffer
        if (it < ITERS - 1)
            *(floatx2*)&xs[cur ^ 1][srow * XROW + scol2] = pre;
        __syncthreads();

        // ---- reduce 4 partials; thread owns elems [2*tid, 2*tid+1] ----
        const float* rb = red[cur];
        floatx2 sum = *(const floatx2*)(rb + srow * 34 + scol2);
        #pragma unroll
        for (int w = 1; w < 4; ++w) {
            floatx2 pp = *(const floatx2*)(rb + w * REDW + srow * 34 + scol2);
            sum.x += pp.x; sum.y += pp.y;
        }
        *(floatx2*)(out + (size_t)b0 * 32 + tid * 2) = sum;
        // next tile writes the other red/xs buffers; barrier orders reuse
    }
}

extern "C" void kernel_launch(void* const* d_in, const int* in_sizes, int n_in,
                              void* d_out, int out_size, void* d_ws, size_t ws_size,
                              hipStream_t stream) {
    const float* x    = (const float*)d_in[0];
    const float* Wlin = (const float*)d_in[1];
    const float* Wnl  = (const float*)d_in[2];
    float* out        = (float*)d_out;
    nnode_kernel<<<dim3(GRID), dim3(256), 0, stream>>>(x, Wlin, Wnl, out);
}